// Round 3
// baseline (5840.816 us; speedup 1.0000x reference)
//
#include <hip/hip_runtime.h>
#include <hip/hip_fp16.h>

#define BB 128
#define II 64
#define SS 2048
#define HH 128
#define GG 512   // 4*H
#define OO 64

typedef _Float16 f16x2 __attribute__((ext_vector_type(2)));
union F4H { float4 f4; f16x2 h[4]; };

__device__ __forceinline__ f16x2 pack2(float a, float b) {
    f16x2 r; r.x = (_Float16)a; r.y = (_Float16)b; return r;
}
__device__ __forceinline__ float dot2(f16x2 w, f16x2 v, float c) {
    return __builtin_amdgcn_fdot2(w, v, c, false);
}
__device__ __forceinline__ float sigm(float v) {
    return __builtin_amdgcn_rcpf(1.0f + __expf(-v));
}
__device__ __forceinline__ float tanh_f(float v) {
    float a = fabsf(v);
    float e = __expf(-2.0f * a);
    float r = (1.0f - e) * __builtin_amdgcn_rcpf(1.0f + e);
    return v < 0.0f ? -r : r;
}

// One block per batch element, 512 threads, thread j owns gate column j.
// Wh_out/Wx_in/Wh_in fp16 in registers, PINNED via empty asm so the
// allocator cannot rematerialize the loads into the loop (round 2: VGPR
// stayed 128 and ~390 redundant cvt/pack VALU insts/thread/step appeared).
// waves_per_eu(2,2): occupancy target exactly 2 waves/EU -> 256-VGPR budget
// (LDS of 87 KB limits us to 1 block/CU anyway, so no occupancy loss).
__global__ void __launch_bounds__(512)
__attribute__((amdgpu_waves_per_eu(2, 2)))
nlstm_scan(
    const float* __restrict__ x,
    const float* __restrict__ Wx_out, const float* __restrict__ Wh_out,
    const float* __restrict__ b_out,
    const float* __restrict__ Wx_in, const float* __restrict__ Wh_in,
    const float* __restrict__ b_in,
    const float* __restrict__ W_lin, const float* __restrict__ b_lin,
    float* __restrict__ out)
{
    const int b = blockIdx.x;
    const int j = threadIdx.x;

    // Wx_out fp16, chunk-major: chunk c (k=8c..8c+8) of column j at wxf[c*512+j].
    __shared__ __align__(16) float4 wxf[8 * 512];          // 64 KB
    // W_lin fp16, chunk-major padded: chunk c of row pn at wlf[c*66+pn].
    __shared__ __align__(16) float4 wlf[16 * 66];          // 16.9 KB
    __shared__ __align__(16) f16x2 xb[2][II / 2];          // x_t fp16, dbuf
    __shared__ __align__(16) f16x2 hb[HH / 2];             // h fp16
    __shared__ __align__(16) f16x2 xib[HH / 2];            // x_in fp16
    __shared__ __align__(16) f16x2 hib[HH / 2];            // h_in fp16
    __shared__ __align__(16) float cb[HH];                 // outer cell fp32
    __shared__ __align__(16) float cnb[HH];                // inner cell fp32
    __shared__ __align__(16) float actO[GG];
    __shared__ __align__(16) float actI[GG];

    // ---- register-resident fp16 weights (column j) : 192 VGPRs ----
    f16x2 who[HH / 2];   // Wh_out col j
    f16x2 wxi[HH / 2];   // Wx_in  col j
    f16x2 whi[HH / 2];   // Wh_in  col j
#pragma unroll
    for (int m = 0; m < HH / 2; ++m)
        who[m] = pack2(Wh_out[(2 * m) * GG + j], Wh_out[(2 * m + 1) * GG + j]);
#pragma unroll
    for (int m = 0; m < HH / 2; ++m)
        wxi[m] = pack2(Wx_in[(2 * m) * GG + j], Wx_in[(2 * m + 1) * GG + j]);
#pragma unroll
    for (int m = 0; m < HH / 2; ++m)
        whi[m] = pack2(Wh_in[(2 * m) * GG + j], Wh_in[(2 * m + 1) * GG + j]);

    // Pin: values become asm-defined -> cannot be rematerialized from the
    // global loads; allocator must keep them live (budget 256 suffices).
#pragma unroll
    for (int m = 0; m < HH / 2; ++m) {
        float t0 = __builtin_bit_cast(float, who[m]);
        float t1 = __builtin_bit_cast(float, wxi[m]);
        float t2 = __builtin_bit_cast(float, whi[m]);
        asm volatile("" : "+v"(t0), "+v"(t1), "+v"(t2));
        who[m] = __builtin_bit_cast(f16x2, t0);
        wxi[m] = __builtin_bit_cast(f16x2, t1);
        whi[m] = __builtin_bit_cast(f16x2, t2);
    }

    const float bo = b_out[j];
    const float bi = b_in[j];
    const int   pn = j >> 3;
    const int   ps = j & 7;
    const float bl = b_lin[pn];

    // Wx_out -> LDS fp16 (thread j converts its own column)
#pragma unroll
    for (int c = 0; c < 8; ++c) {
        F4H u;
#pragma unroll
        for (int q = 0; q < 4; ++q)
            u.h[q] = pack2(Wx_out[(8 * c + 2 * q) * GG + j],
                           Wx_out[(8 * c + 2 * q + 1) * GG + j]);
        wxf[c * 512 + j] = u.f4;
    }
    // W_lin -> LDS fp16 (1024 chunks, 2 per thread)
#pragma unroll
    for (int r = 0; r < 2; ++r) {
        const int m = r * 512 + j;
        const int c = m >> 6, n = m & 63;
        F4H u;
#pragma unroll
        for (int q = 0; q < 4; ++q)
            u.h[q] = pack2(W_lin[n * HH + 8 * c + 2 * q],
                           W_lin[n * HH + 8 * c + 2 * q + 1]);
        wlf[c * 66 + n] = u.f4;
    }

    const float* xrow = x + (size_t)b * II * SS;   // x[b,i,t] = xrow[i*SS + t]
    float* orow = out + (size_t)b * SS * OO;

    if (j < HH / 2) hb[j] = pack2(0.f, 0.f);
    if (j < HH) { cb[j] = 0.f; cnb[j] = 0.f; }
    if (j < II / 2)  // stage x for t=0
        xb[0][j] = pack2(xrow[(2 * j) * SS], xrow[(2 * j + 1) * SS]);
    __syncthreads();

    const float4* hb4 = (const float4*)hb;   // 16 chunks
    const float4* xi4 = (const float4*)xib;
    const float4* hi4 = (const float4*)hib;

#pragma unroll 1
    for (int t = 0; t < SS; ++t) {
        const float4* xb4 = (const float4*)xb[t & 1];   // 8 chunks

        // ---- P1: outer gates: col j of xt@Wx_out + h@Wh_out + b ----
        float acc = bo;
#pragma unroll
        for (int c = 0; c < 8; ++c) {
            F4H xu; xu.f4 = xb4[c];
            F4H wu; wu.f4 = wxf[c * 512 + j];
            acc = dot2(wu.h[0], xu.h[0], acc);
            acc = dot2(wu.h[1], xu.h[1], acc);
            acc = dot2(wu.h[2], xu.h[2], acc);
            acc = dot2(wu.h[3], xu.h[3], acc);
        }
#pragma unroll
        for (int c = 0; c < 16; ++c) {
            F4H hu; hu.f4 = hb4[c];
            acc = dot2(who[4 * c + 0], hu.h[0], acc);
            acc = dot2(who[4 * c + 1], hu.h[1], acc);
            acc = dot2(who[4 * c + 2], hu.h[2], acc);
            acc = dot2(who[4 * c + 3], hu.h[3], acc);
        }
        actO[j] = (j < 384) ? sigm(acc) : tanh_f(acc);
        __syncthreads();   // B1

        // ---- P2: form x_in / h_in; prefetch x for t+1 ----
        if (j < II) {
            xib[j] = pack2(actO[2 * j] * actO[384 + 2 * j],
                           actO[2 * j + 1] * actO[384 + 2 * j + 1]);
        } else if (j < II + HH / 2) {
            const int m = j - II;
            hib[m] = pack2(actO[128 + 2 * m] * cb[2 * m],
                           actO[128 + 2 * m + 1] * cb[2 * m + 1]);
        } else if (j < II + HH / 2 + II / 2 && t + 1 < SS) {
            const int m = j - (II + HH / 2);
            xb[(t + 1) & 1][m] = pack2(xrow[(2 * m) * SS + t + 1],
                                       xrow[(2 * m + 1) * SS + t + 1]);
        }
        __syncthreads();   // B2

        // ---- P3: inner gates: col j of x_in@Wx_in + h_in@Wh_in + b ----
        float acc2 = bi;
#pragma unroll
        for (int c = 0; c < 16; ++c) {
            F4H xu; xu.f4 = xi4[c];
            acc2 = dot2(wxi[4 * c + 0], xu.h[0], acc2);
            acc2 = dot2(wxi[4 * c + 1], xu.h[1], acc2);
            acc2 = dot2(wxi[4 * c + 2], xu.h[2], acc2);
            acc2 = dot2(wxi[4 * c + 3], xu.h[3], acc2);
        }
#pragma unroll
        for (int c = 0; c < 16; ++c) {
            F4H hu; hu.f4 = hi4[c];
            acc2 = dot2(whi[4 * c + 0], hu.h[0], acc2);
            acc2 = dot2(whi[4 * c + 1], hu.h[1], acc2);
            acc2 = dot2(whi[4 * c + 2], hu.h[2], acc2);
            acc2 = dot2(whi[4 * c + 3], hu.h[3], acc2);
        }
        actI[j] = (j < 384) ? sigm(acc2) : tanh_f(acc2);
        __syncthreads();   // B3

        // ---- P4: state update (threads 0..127) ----
        if (j < HH) {
            const float cn_new = actI[HH + j] * cnb[j] + actI[j] * actI[384 + j];
            const float c_new  = actI[2 * HH + j] * tanh_f(cn_new);
            const float h_new  = actO[2 * HH + j] * tanh_f(c_new);
            cnb[j] = cn_new;
            cb[j]  = c_new;
            ((_Float16*)hb)[j] = (_Float16)h_new;
        }
        __syncthreads();   // B4

        // ---- P5: fused projection: out[b,t,pn] = h @ W_lin[pn,:] + b ----
        // (reads hb/wlf only; next P1 also only reads hb -> no extra barrier)
        float p = 0.f;
#pragma unroll
        for (int q = 0; q < 2; ++q) {
            const int c = 2 * ps + q;
            F4H hu; hu.f4 = hb4[c];
            F4H wu; wu.f4 = wlf[c * 66 + pn];
            p = dot2(wu.h[0], hu.h[0], p);
            p = dot2(wu.h[1], hu.h[1], p);
            p = dot2(wu.h[2], hu.h[2], p);
            p = dot2(wu.h[3], hu.h[3], p);
        }
        p += __shfl_down(p, 4, 8);
        p += __shfl_down(p, 2, 8);
        p += __shfl_down(p, 1, 8);
        if (ps == 0) orow[t * OO + pn] = p + bl;
    }
}

extern "C" void kernel_launch(void* const* d_in, const int* in_sizes, int n_in,
                              void* d_out, int out_size, void* d_ws, size_t ws_size,
                              hipStream_t stream) {
    (void)in_sizes; (void)n_in; (void)d_ws; (void)ws_size; (void)out_size;
    const float* x      = (const float*)d_in[0];
    const float* Wx_out = (const float*)d_in[1];
    const float* Wh_out = (const float*)d_in[2];
    const float* b_out  = (const float*)d_in[3];
    const float* Wx_in  = (const float*)d_in[4];
    const float* Wh_in  = (const float*)d_in[5];
    const float* b_in   = (const float*)d_in[6];
    const float* W_lin  = (const float*)d_in[7];
    const float* b_lin  = (const float*)d_in[8];
    float* out = (float*)d_out;

    nlstm_scan<<<dim3(BB), dim3(512), 0, stream>>>(
        x, Wx_out, Wh_out, b_out, Wx_in, Wh_in, b_in, W_lin, b_lin, out);
}